// Round 9
// baseline (1401.065 us; speedup 1.0000x reference)
//
#include <hip/hip_runtime.h>
#include <hip/hip_cooperative_groups.h>

namespace cg = cooperative_groups;

// BigraphLightModel — R14: cooperative mega-kernel (persistent blocks).
//   R13 post-mortem: dispatch-level role fusion = sum(roles) not max(roles)
//   (interleave bought ~3us; 4 rounds of overlap scheduling = 19us total).
//   cvt2s is a SCATTER-store role (sorted positions) — R13's f_fill_cvts
//   pairing was scatter+scatter = toxic (52-55us).
//   This round: ONE hipLaunchCooperativeKernel for build+g1+prep.
//   Persistent blocks co-resident from t=0; stages separated by grid.sync()
//   (~2-5us) instead of dispatch drains; within a stage each block runs
//   role A then role B => genuine CU-level atomic/BW mixing.
//   Stages: Z zero | S0 cvt1|cnt1|cnt2a | S1-S5 {node1,fill1,deg1,valsc1,
//   spmm1_g1}|cnt2b..f | S6 spmm2_g1|node2 | S7 fill2|cvt2s |
//   S8 final1|deg2|sortfin2 | S9 evnorm. Tail: 3 regular launches (g2 chain).
//   Facts bank: scattered atomicAdd ~20-24G/s invariant (R7/R8); sorted-space
//   g2 (R10); k_final_s 47us@123MB = gather-fabric roofline (R12).

#define D       64
#define N_II    100000
#define N_UIU   200000
#define E_II    600000
#define E_UIU   1200000
#define N_USERS 100000
#define B       256

#define NB1   ((N_II + B - 1) / B)        // 391 node-blocks g1
#define NB2   ((N_UIU + B - 1) / B)       // 782 node-blocks g2
#define NS1B  ((N_II * 8 + B - 1) / B)    // 3125 spmm/final1 blocks g1
#define NCVTB ((N_USERS * 8 + B - 1) / B) // 3125 cvt2s blocks

// ---------- bf16 helpers ----------
__device__ __forceinline__ unsigned short f2bf(float f) {
    unsigned u = __float_as_uint(f);
    u += 0x7fffu + ((u >> 16) & 1u);          // round-to-nearest-even
    return (unsigned short)(u >> 16);
}
__device__ __forceinline__ void bf8_fma(float acc[8], uint4 p, float v) {
    acc[0] += v * __uint_as_float(p.x << 16);
    acc[1] += v * __uint_as_float(p.x & 0xffff0000u);
    acc[2] += v * __uint_as_float(p.y << 16);
    acc[3] += v * __uint_as_float(p.y & 0xffff0000u);
    acc[4] += v * __uint_as_float(p.z << 16);
    acc[5] += v * __uint_as_float(p.z & 0xffff0000u);
    acc[6] += v * __uint_as_float(p.w << 16);
    acc[7] += v * __uint_as_float(p.w & 0xffff0000u);
}
__device__ __forceinline__ void bf8_add(float acc[8], uint4 p) {
    acc[0] += __uint_as_float(p.x << 16);
    acc[1] += __uint_as_float(p.x & 0xffff0000u);
    acc[2] += __uint_as_float(p.y << 16);
    acc[3] += __uint_as_float(p.y & 0xffff0000u);
    acc[4] += __uint_as_float(p.z << 16);
    acc[5] += __uint_as_float(p.z & 0xffff0000u);
    acc[6] += __uint_as_float(p.w << 16);
    acc[7] += __uint_as_float(p.w & 0xffff0000u);
}
__device__ __forceinline__ uint4 pack8(const float a[8]) {
    uint4 r;
    r.x = (unsigned)f2bf(a[0]) | ((unsigned)f2bf(a[1]) << 16);
    r.y = (unsigned)f2bf(a[2]) | ((unsigned)f2bf(a[3]) << 16);
    r.z = (unsigned)f2bf(a[4]) | ((unsigned)f2bf(a[5]) << 16);
    r.w = (unsigned)f2bf(a[6]) | ((unsigned)f2bf(a[7]) << 16);
    return r;
}
__device__ __forceinline__ int bin_of(int c) { return (c < 63) ? c : 63; }

// exclusive scan of ghist[64] into shared sboff[64] (wave 0); caller syncs.
__device__ __forceinline__ void scan_boff(const int* __restrict__ ghist, int* sboff) {
    int t = threadIdx.x;
    if (t < 64) {
        int v = ghist[t];
        int s = v;
        for (int o = 1; o < 64; o <<= 1) {
            int u = __shfl_up(s, o);
            if (t >= o) s += u;
        }
        sboff[t] = s - v;
    }
}

// ---------- block-structured role bodies (persistent-loop safe: no returns,
// trailing __syncthreads protects shared reuse across loop iterations) ----------

__device__ void node_block(int vb, const int* __restrict__ cnt, int2* __restrict__ rr,
                           int* __restrict__ brk, int* __restrict__ ghist,
                           int* __restrict__ gcur, int N) {
    __shared__ int sh[B];
    __shared__ int h[64], hb[64];
    __shared__ int sbase;
    int t = threadIdx.x;
    int i = vb * B + t;
    int c = (i < N) ? cnt[i] : 0;
    int b = bin_of(c);
    sh[t] = c;
    if (t < 64) h[t] = 0;
    __syncthreads();
    int rk = 0;
    if (i < N) rk = atomicAdd(&h[b], 1);
    for (int off = 1; off < B; off <<= 1) {   // inclusive scan
        int u = (t >= off) ? sh[t - off] : 0;
        __syncthreads();
        sh[t] += u;
        __syncthreads();
    }
    if (t == B - 1) sbase = atomicAdd(gcur, sh[B - 1]);
    if (t < 64) hb[t] = h[t] ? atomicAdd(&ghist[t], h[t]) : 0;
    __syncthreads();
    if (i < N) {
        int o = sbase + sh[t] - c;
        rr[i] = make_int2(o, o + c);
        brk[i] = hb[b] + rk;
    }
    __syncthreads();
}

__device__ void valsc_block(int vb, const int2* __restrict__ rr, const float* __restrict__ dis,
                            const int* __restrict__ brk, const int* __restrict__ ghist,
                            int2* __restrict__ ev, int* __restrict__ perm,
                            int2* __restrict__ rrp, int N) {
    __shared__ int sboff[64];
    scan_boff(ghist, sboff);
    __syncthreads();
    int i = vb * B + threadIdx.x;
    if (i < N) {
        int2 se = rr[i];
        float di = dis[i];
        for (int j = se.x; j < se.y; ++j) {
            int2 pp = ev[j];
            ev[j].y = __float_as_int(di * __int_as_float(pp.y) * dis[pp.x]);
        }
        int pos = sboff[bin_of(se.y - se.x)] + brk[i];
        perm[pos] = i;
        rrp[pos]  = se;
    }
    __syncthreads();
}

__device__ void sortfin_block(int vb, const int2* __restrict__ rr, const int* __restrict__ brk,
                              const int* __restrict__ ghist, int* __restrict__ sortpos,
                              int* __restrict__ perm, int2* __restrict__ srr, int N) {
    __shared__ int sboff[64];
    scan_boff(ghist, sboff);
    __syncthreads();
    int i = vb * B + threadIdx.x;
    if (i < N) {
        int2 se = rr[i];
        int pos = sboff[bin_of(se.y - se.x)] + brk[i];
        sortpos[i] = pos;
        perm[pos] = i;
        srr[pos]  = se;
    }
    __syncthreads();
}

__device__ void cvts_block(int vb, const float4* __restrict__ xu,
                           const int2* __restrict__ rr2, const int* __restrict__ brk2,
                           const int* __restrict__ ghist2, uint4* __restrict__ xb0s) {
    __shared__ int sboff[64];
    scan_boff(ghist2, sboff);
    __syncthreads();
    int idx = vb * B + threadIdx.x;
    int row = idx >> 3;
    if (row < N_USERS) {
        int g = idx & 7;
        int2 s2 = rr2[row];
        int pos = sboff[bin_of(s2.y - s2.x)] + brk2[row];
        float4 a = xu[(size_t)row * 16 + 2 * g], b = xu[(size_t)row * 16 + 2 * g + 1];
        float tv[8] = {a.x, a.y, a.z, a.w, b.x, b.y, b.z, b.w};
        xb0s[(size_t)pos * 8 + g] = pack8(tv);
    }
    __syncthreads();
}

__device__ void final1_block(int vb, const int2* __restrict__ rrp, const int* __restrict__ perm,
                             const int2* __restrict__ ev, const uint4* __restrict__ x2b,
                             const uint4* __restrict__ x1b, const uint4* __restrict__ x0b,
                             const int2* __restrict__ rr2, const int* __restrict__ brk2,
                             const int* __restrict__ ghist2, uint4* __restrict__ xb0s,
                             float alpha) {
    __shared__ int sboff[64];
    scan_boff(ghist2, sboff);
    __syncthreads();
    int idx = vb * B + threadIdx.x;
    int vrow = idx >> 3;
    if (vrow < N_II) {
        int g = idx & 7;
        int2 se = rrp[vrow];
        int row = perm[vrow];
        float acc[8] = {0.f, 0.f, 0.f, 0.f, 0.f, 0.f, 0.f, 0.f};
        int j = se.x, e = se.y;
        for (; j + 3 < e; j += 4) {
            int2 p0 = ev[j], p1 = ev[j + 1], p2 = ev[j + 2], p3 = ev[j + 3];
            uint4 a0 = x2b[(size_t)p0.x * 8 + g];
            uint4 a1 = x2b[(size_t)p1.x * 8 + g];
            uint4 a2 = x2b[(size_t)p2.x * 8 + g];
            uint4 a3 = x2b[(size_t)p3.x * 8 + g];
            bf8_fma(acc, a0, __int_as_float(p0.y));
            bf8_fma(acc, a1, __int_as_float(p1.y));
            bf8_fma(acc, a2, __int_as_float(p2.y));
            bf8_fma(acc, a3, __int_as_float(p3.y));
        }
        for (; j < e; ++j) {
            int2 p0 = ev[j];
            uint4 a0 = x2b[(size_t)p0.x * 8 + g];
            bf8_fma(acc, a0, __int_as_float(p0.y));
        }
        bf8_add(acc, x1b[(size_t)row * 8 + g]);
        bf8_add(acc, x2b[(size_t)row * 8 + g]);
        bf8_add(acc, x0b[(size_t)row * 8 + g]);
        float r[8];
#pragma unroll
        for (int k = 0; k < 8; ++k) r[k] = alpha * acc[k];
        int oi = N_USERS + row;                   // orig id in g2 space
        int2 s2 = rr2[oi];
        int pos = sboff[bin_of(s2.y - s2.x)] + brk2[oi];
        xb0s[(size_t)pos * 8 + g] = pack8(r);
    }
    __syncthreads();
}

// grid-stride pull SpMM (g1, orig-space with perm indirection)
__device__ void spmm_gs(int gtid, int gsz, const int2* __restrict__ rrp,
                        const int* __restrict__ perm, const int2* __restrict__ ev,
                        const uint4* __restrict__ xb, uint4* __restrict__ xn, int N) {
    for (int idx = gtid; idx < N * 8; idx += gsz) {
        int vrow = idx >> 3;
        int g = idx & 7;
        int2 se = rrp[vrow];
        int row = perm[vrow];
        float acc[8] = {0.f, 0.f, 0.f, 0.f, 0.f, 0.f, 0.f, 0.f};
        int j = se.x, e = se.y;
        for (; j + 3 < e; j += 4) {
            int2 p0 = ev[j], p1 = ev[j + 1], p2 = ev[j + 2], p3 = ev[j + 3];
            uint4 a0 = xb[(size_t)p0.x * 8 + g];
            uint4 a1 = xb[(size_t)p1.x * 8 + g];
            uint4 a2 = xb[(size_t)p2.x * 8 + g];
            uint4 a3 = xb[(size_t)p3.x * 8 + g];
            bf8_fma(acc, a0, __int_as_float(p0.y));
            bf8_fma(acc, a1, __int_as_float(p1.y));
            bf8_fma(acc, a2, __int_as_float(p2.y));
            bf8_fma(acc, a3, __int_as_float(p3.y));
        }
        for (; j < e; ++j) {
            int2 p0 = ev[j];
            uint4 a0 = xb[(size_t)p0.x * 8 + g];
            bf8_fma(acc, a0, __int_as_float(p0.y));
        }
        xn[(size_t)row * 8 + g] = pack8(acc);
    }
}

// ---------- cooperative mega-kernel ----------

struct MegaP {
    const int *src1, *dst1; const float *w1;
    const int *src2, *dst2; const float *w2;
    const float4 *emb1; const float4 *embu;
    int *cnt1; int *rank1; int2 *rr1; int *brk1; float *dis1;
    int *perm1; int2 *rrp1; int2 *ev1;
    int *cnt2; int *rank2; int2 *rr2; int *brk2; float *dis2;
    int *sortpos2; int *perm2; int2 *srr2; int2 *ev2;
    uint4 *g1x0, *g1x1, *g1x2, *xb0s;
    float alpha;
    int c1, c2, c3, c4, c5;   // cnt2 slice boundaries (c0=0, c6=E_UIU)
};

__global__ void __launch_bounds__(B) mega(MegaP p) {
    cg::grid_group gr = cg::this_grid();
    const int gsz  = (int)gridDim.x * B;
    const int gtid = (int)(blockIdx.x * B + threadIdx.x);
    int* gt1 = p.cnt1 + N_II;    // gcur | ghist[64] | spare
    int* gt2 = p.cnt2 + N_UIU;

    // Z: zero counters (+gcur/ghist tails)
    for (int i = gtid; i < N_II + 129;  i += gsz) p.cnt1[i] = 0;
    for (int i = gtid; i < N_UIU + 129; i += gsz) p.cnt2[i] = 0;
    gr.sync();

    // S0: cvt1 | cnt1 | cnt2[0,c1)
    for (int i = gtid; i < N_II * 8; i += gsz) {
        float4 a = p.emb1[2 * i], b = p.emb1[2 * i + 1];
        float tv[8] = {a.x, a.y, a.z, a.w, b.x, b.y, b.z, b.w};
        p.g1x0[i] = pack8(tv);
    }
    for (int e = gtid; e < E_II; e += gsz)
        p.rank1[e] = atomicAdd(&p.cnt1[p.dst1[e]], 1);
    for (int e = gtid; e < p.c1; e += gsz)
        p.rank2[e] = atomicAdd(&p.cnt2[p.dst2[e]], 1);
    gr.sync();

    // S1: node1 | cnt2[c1,c2)
    for (int vb = (int)blockIdx.x; vb < NB1; vb += (int)gridDim.x)
        node_block(vb, p.cnt1, p.rr1, p.brk1, gt1 + 1, gt1, N_II);
    for (int e = p.c1 + gtid; e < p.c2; e += gsz)
        p.rank2[e] = atomicAdd(&p.cnt2[p.dst2[e]], 1);
    gr.sync();

    // S2: fill1 | cnt2[c2,c3)
    for (int e = gtid; e < E_II; e += gsz) {
        int d = p.dst1[e];
        int pos = p.rr1[d].x + p.rank1[e];
        p.ev1[pos] = make_int2(p.src1[e], __float_as_int(p.w1[e]));
    }
    for (int e = p.c2 + gtid; e < p.c3; e += gsz)
        p.rank2[e] = atomicAdd(&p.cnt2[p.dst2[e]], 1);
    gr.sync();

    // S3: deg1 | cnt2[c3,c4)
    for (int i = gtid; i < N_II; i += gsz) {
        int2 se = p.rr1[i];
        float dg = 0.f;
        for (int j = se.x; j < se.y; ++j) dg += __int_as_float(p.ev1[j].y);
        p.dis1[i] = (dg > 0.f) ? rsqrtf(dg) : 0.f;
    }
    for (int e = p.c3 + gtid; e < p.c4; e += gsz)
        p.rank2[e] = atomicAdd(&p.cnt2[p.dst2[e]], 1);
    gr.sync();

    // S4: valsc1 | cnt2[c4,c5)   (perm1/rrp1 alias rank1: last read S2 — safe)
    for (int vb = (int)blockIdx.x; vb < NB1; vb += (int)gridDim.x)
        valsc_block(vb, p.rr1, p.dis1, p.brk1, gt1 + 1, p.ev1, p.perm1, p.rrp1, N_II);
    for (int e = p.c4 + gtid; e < p.c5; e += gsz)
        p.rank2[e] = atomicAdd(&p.cnt2[p.dst2[e]], 1);
    gr.sync();

    // S5: spmm1_g1 | cnt2[c5,E)  (cnt2 complete after this stage)
    spmm_gs(gtid, gsz, p.rrp1, p.perm1, p.ev1, p.g1x0, p.g1x1, N_II);
    for (int e = p.c5 + gtid; e < E_UIU; e += gsz)
        p.rank2[e] = atomicAdd(&p.cnt2[p.dst2[e]], 1);
    gr.sync();

    // S6: spmm2_g1 | node2
    spmm_gs(gtid, gsz, p.rrp1, p.perm1, p.ev1, p.g1x1, p.g1x2, N_II);
    for (int vb = (int)blockIdx.x; vb < NB2; vb += (int)gridDim.x)
        node_block(vb, p.cnt2, p.rr2, p.brk2, gt2 + 1, gt2, N_UIU);
    gr.sync();

    // S7: fill2 | cvt2s (user rows -> sorted bf16 x0)
    for (int e = gtid; e < E_UIU; e += gsz) {
        int d = p.dst2[e];
        int pos = p.rr2[d].x + p.rank2[e];
        p.ev2[pos] = make_int2(p.src2[e], __float_as_int(p.w2[e]));
    }
    for (int vb = (int)blockIdx.x; vb < NCVTB; vb += (int)gridDim.x)
        cvts_block(vb, p.embu, p.rr2, p.brk2, gt2 + 1, p.xb0s);
    gr.sync();

    // S8: final1 (item rows -> sorted x0) | deg2 | sortfin2
    //     (perm2/srr2 alias rank2: last read S7; sortpos2 aliases cnt2: last read S6)
    for (int vb = (int)blockIdx.x; vb < NS1B; vb += (int)gridDim.x)
        final1_block(vb, p.rrp1, p.perm1, p.ev1, p.g1x2, p.g1x1, p.g1x0,
                     p.rr2, p.brk2, gt2 + 1, p.xb0s, p.alpha);
    for (int i = gtid; i < N_UIU; i += gsz) {
        int2 se = p.rr2[i];
        float dg = 0.f;
        for (int j = se.x; j < se.y; ++j) dg += __int_as_float(p.ev2[j].y);
        p.dis2[i] = (dg > 0.f) ? rsqrtf(dg) : 0.f;
    }
    for (int vb = (int)blockIdx.x; vb < NB2; vb += (int)gridDim.x)
        sortfin_block(vb, p.rr2, p.brk2, gt2 + 1, p.sortpos2, p.perm2, p.srr2, N_UIU);
    gr.sync();

    // S9: evnorm2 (normalize + remap ev.x -> sorted space)
    for (int i = gtid; i < N_UIU; i += gsz) {
        int2 se = p.rr2[i];
        float di = p.dis2[i];
        for (int j = se.x; j < se.y; ++j) {
            int2 pp = p.ev2[j];
            p.ev2[j] = make_int2(p.sortpos2[pp.x],
                                 __float_as_int(di * __int_as_float(pp.y) * p.dis2[pp.x]));
        }
    }
}

// ---------- tail kernels (regular launches; sorted-space g2 chain) ----------

__global__ void k_spmm_s(const int2* __restrict__ srr, const int2* __restrict__ ev,
                         const uint4* __restrict__ xb, uint4* __restrict__ xn, int N) {
    int idx = (int)(blockIdx.x * B + threadIdx.x);
    int vrow = idx >> 3;
    if (vrow >= N) return;
    int g = idx & 7;
    int2 se = srr[vrow];
    float acc[8] = {0.f, 0.f, 0.f, 0.f, 0.f, 0.f, 0.f, 0.f};
    int j = se.x, e = se.y;
    for (; j + 3 < e; j += 4) {
        int2 p0 = ev[j], p1 = ev[j + 1], p2 = ev[j + 2], p3 = ev[j + 3];
        uint4 a0 = xb[(size_t)p0.x * 8 + g];
        uint4 a1 = xb[(size_t)p1.x * 8 + g];
        uint4 a2 = xb[(size_t)p2.x * 8 + g];
        uint4 a3 = xb[(size_t)p3.x * 8 + g];
        bf8_fma(acc, a0, __int_as_float(p0.y));
        bf8_fma(acc, a1, __int_as_float(p1.y));
        bf8_fma(acc, a2, __int_as_float(p2.y));
        bf8_fma(acc, a3, __int_as_float(p3.y));
    }
    for (; j < e; ++j) {
        int2 p0 = ev[j];
        uint4 a0 = xb[(size_t)p0.x * 8 + g];
        bf8_fma(acc, a0, __int_as_float(p0.y));
    }
    xn[(size_t)vrow * 8 + g] = pack8(acc);
}

__global__ void k_final_s(const int2* __restrict__ srr, const int* __restrict__ perm,
                          const int2* __restrict__ ev, const uint4* __restrict__ x2s,
                          const uint4* __restrict__ x1s, const uint4* __restrict__ x0s,
                          float4* __restrict__ out, float alpha, int N) {
    int idx = (int)(blockIdx.x * B + threadIdx.x);
    int vrow = idx >> 3;
    if (vrow >= N) return;
    int g = idx & 7;
    int2 se = srr[vrow];
    float acc[8] = {0.f, 0.f, 0.f, 0.f, 0.f, 0.f, 0.f, 0.f};
    int j = se.x, e = se.y;
    for (; j + 3 < e; j += 4) {
        int2 p0 = ev[j], p1 = ev[j + 1], p2 = ev[j + 2], p3 = ev[j + 3];
        uint4 a0 = x2s[(size_t)p0.x * 8 + g];
        uint4 a1 = x2s[(size_t)p1.x * 8 + g];
        uint4 a2 = x2s[(size_t)p2.x * 8 + g];
        uint4 a3 = x2s[(size_t)p3.x * 8 + g];
        bf8_fma(acc, a0, __int_as_float(p0.y));
        bf8_fma(acc, a1, __int_as_float(p1.y));
        bf8_fma(acc, a2, __int_as_float(p2.y));
        bf8_fma(acc, a3, __int_as_float(p3.y));
    }
    for (; j < e; ++j) {
        int2 p0 = ev[j];
        uint4 a0 = x2s[(size_t)p0.x * 8 + g];
        bf8_fma(acc, a0, __int_as_float(p0.y));
    }
    bf8_add(acc, x1s[(size_t)vrow * 8 + g]);
    bf8_add(acc, x2s[(size_t)vrow * 8 + g]);
    bf8_add(acc, x0s[(size_t)vrow * 8 + g]);
    float r[8];
#pragma unroll
    for (int k = 0; k < 8; ++k) r[k] = alpha * acc[k];
    int orig = perm[vrow];
    out[(size_t)orig * 16 + 2 * g]     = make_float4(r[0], r[1], r[2], r[3]);
    out[(size_t)orig * 16 + 2 * g + 1] = make_float4(r[4], r[5], r[6], r[7]);
}

// ---------- host-side orchestration ----------

static inline int nbx(long long work, int per) { return (int)((work + per - 1) / per); }

extern "C" void kernel_launch(void* const* d_in, const int* in_sizes, int n_in,
                              void* d_out, int out_size, void* d_ws, size_t ws_size,
                              hipStream_t stream) {
    const float* emb_ii  = (const float*)d_in[0];
    const float* emb_uiu = (const float*)d_in[1];
    const float* w_ii    = (const float*)d_in[2];
    const float* w_uiu   = (const float*)d_in[3];
    const int*   src_ii  = (const int*)d_in[4];
    const int*   dst_ii  = src_ii + E_II;
    const int*   src_uiu = (const int*)d_in[5];
    const int*   dst_uiu = src_uiu + E_UIU;
    float*       out     = (float*)d_out;

    // ---- workspace (95.2 MB, layout identical to R12) ----
    uint4* xb0_u = (uint4*)d_ws;
    uint4* x1_u  = xb0_u + (size_t)N_UIU * 8;
    uint4* x2_u  = x1_u + (size_t)N_UIU * 8;

    // g1 build block in x2_u second half (dead after S8; overwritten by g2 spmm2 launch)
    int2*  ev1   = (int2*)(x2_u + (size_t)N_II * 8);
    int*   rank1 = (int*)(ev1 + E_II);
    int2*  rr1   = (int2*)(rank1 + E_II);
    int*   cnt1  = (int*)(rr1 + N_II);          // + gt1[129] contiguous
    float* dis1  = (float*)(cnt1 + N_II + 129);
    int*   brk1  = (int*)(dis1 + N_II);
    int*   perm1 = rank1;                       // alias (rank1 dead after S2)
    int2*  rrp1  = (int2*)(rank1 + N_II);

    // g2 build block (tail)
    int2*  ev2   = (int2*)(x2_u + (size_t)N_UIU * 8);
    int*   rank2 = (int*)(ev2 + E_UIU);
    int*   perm2 = rank2;                       // alias (rank2 dead after S7)
    int2*  srr2  = (int2*)(rank2 + N_UIU);
    int2*  rr2   = (int2*)(rank2 + E_UIU);
    int*   cnt2  = (int*)(rr2 + N_UIU);         // + gt2[129] contiguous
    int*   sortpos2 = cnt2;                     // alias (cnt2 dead after S6)
    int*   brk2  = cnt2 + N_UIU + 129;
    float* dis2  = (float*)(brk2 + N_UIU);

    uint4* g1_x0 = x1_u;
    uint4* g1_x1 = x1_u + (size_t)N_II * 8;
    uint4* g1_x2 = x2_u;                        // x2_u first half

    const float alpha = 0.25f;   // 1/(L+1), L=3 both graphs

    // cooperative grid size (cached; occupancy-derived so the launch is legal)
    static int s_grid = 0;
    if (s_grid == 0) {
        int dev = 0;
        hipGetDevice(&dev);
        hipDeviceProp_t prop;
        hipGetDeviceProperties(&prop, dev);
        int mb = 0;
        hipOccupancyMaxActiveBlocksPerMultiprocessor(&mb, mega, B, 0);
        if (mb < 1) mb = 1;
        s_grid = mb * prop.multiProcessorCount;
        if (s_grid < 256) s_grid = 256;
    }

    MegaP p;
    p.src1 = src_ii;  p.dst1 = dst_ii;  p.w1 = w_ii;
    p.src2 = src_uiu; p.dst2 = dst_uiu; p.w2 = w_uiu;
    p.emb1 = (const float4*)emb_ii; p.embu = (const float4*)emb_uiu;
    p.cnt1 = cnt1; p.rank1 = rank1; p.rr1 = rr1; p.brk1 = brk1; p.dis1 = dis1;
    p.perm1 = perm1; p.rrp1 = rrp1; p.ev1 = ev1;
    p.cnt2 = cnt2; p.rank2 = rank2; p.rr2 = rr2; p.brk2 = brk2; p.dis2 = dis2;
    p.sortpos2 = sortpos2; p.perm2 = perm2; p.srr2 = srr2; p.ev2 = ev2;
    p.g1x0 = g1_x0; p.g1x1 = g1_x1; p.g1x2 = g1_x2; p.xb0s = xb0_u;
    p.alpha = alpha;
    p.c1 = 180000; p.c2 = 360000; p.c3 = 540000; p.c4 = 760000; p.c5 = 980000;

    void* args[] = { &p };
    hipLaunchCooperativeKernel(mega, dim3(s_grid), dim3(B), args, 0, stream);

    // g2 spmm chain (sorted space), regular launches
    const int nbS2 = nbx((long long)N_UIU * 8, B);
    k_spmm_s<<<nbS2, B, 0, stream>>>(srr2, ev2, xb0_u, x1_u, N_UIU);
    k_spmm_s<<<nbS2, B, 0, stream>>>(srr2, ev2, x1_u, x2_u, N_UIU);
    k_final_s<<<nbS2, B, 0, stream>>>(srr2, perm2, ev2, x2_u, x1_u, xb0_u,
                                      (float4*)out, alpha, N_UIU);
}

// Round 11
// 484.200 us; speedup vs baseline: 2.8936x; 2.8936x over previous
//
#include <hip/hip_runtime.h>

// BigraphLightModel — R16: int8 row-scaled tables (R12 schedule, bytes halved).
//   R15 post-mortem: fp8-everywhere FAILED accuracy (8.5 > 1.075) — (1) RNE
//   constant bug (+0xFFFFF not +0x7FFFF => +1ULP systematic round-up bias),
//   (2) even correct fp8 = 6.25%/stage x6 stages ~ 2-4 absmax. Fact: plain
//   fp8 tables precision-infeasible; bf16 measures 0.25 vs 1.075 threshold.
//   This round: int8 + per-row fp32 scale (MX-style). Entry error <=
//   rowmax/254 ~ bf16's error at the row max element => predicted absmax
//   0.3-0.6 < 1.075. Row = 64B (one cache line per gather), row-adds halve.
//   Scales: g1 orig-space, g2 sorted-space arrays (L2-resident; one
//   broadcast 4B load per edge, folded into edge weight).
//   Schedule byte-identical to R12 (verified 478.9us best); R15's no-alias
//   workspace + scale arrays = 93.2MB.
//   Facts bank: atomicAdd ~20-24G/s invariant (R7/R8); gather+scatter
//   pairing toxic (R10/R13); fused dispatch ~ sum(roles) (R12/R13);
//   grid.sync = L2 flush (R14); fp8 tables fail accuracy (R15).

#define D       64
#define N_II    100000
#define N_UIU   200000
#define E_II    600000
#define E_UIU   1200000
#define N_USERS 100000
#define B       256
#define CR_K    8
#define FE_K    4

// ---------- int8 row-scale helpers ----------
__device__ __forceinline__ void i8_fma(float acc[8], uint2 p, float vs) {
#pragma unroll
    for (int k = 0; k < 4; ++k)
        acc[k]     += vs * (float)((int)(p.x << (24 - 8 * k)) >> 24);
#pragma unroll
    for (int k = 0; k < 4; ++k)
        acc[4 + k] += vs * (float)((int)(p.y << (24 - 8 * k)) >> 24);
}
__device__ __forceinline__ uint2 pack8i8(const float a[8], float inv) {
    uint2 r; r.x = 0u; r.y = 0u;
#pragma unroll
    for (int k = 0; k < 4; ++k) {
        int q = (int)rintf(a[k] * inv);
        q = max(-127, min(127, q));
        r.x |= ((unsigned)q & 0xffu) << (8 * k);
    }
#pragma unroll
    for (int k = 0; k < 4; ++k) {
        int q = (int)rintf(a[4 + k] * inv);
        q = max(-127, min(127, q));
        r.y |= ((unsigned)q & 0xffu) << (8 * k);
    }
    return r;
}
// absmax over the 8-lane row group (lanes g=0..7 share a row; all role
// grids are exact multiples of 256 so every lane participates)
__device__ __forceinline__ float grp_max8(const float a[8]) {
    float m = 0.f;
#pragma unroll
    for (int k = 0; k < 8; ++k) m = fmaxf(m, fabsf(a[k]));
    m = fmaxf(m, __shfl_xor(m, 1));
    m = fmaxf(m, __shfl_xor(m, 2));
    m = fmaxf(m, __shfl_xor(m, 4));
    return m;
}
// quantize a row fragment + write scale (lane g==0)
__device__ __forceinline__ void store_row_i8(uint2* xb, float* sc, size_t row, int g,
                                             const float a[8]) {
    float m = grp_max8(a);
    float inv = (m > 0.f) ? 127.f / m : 0.f;
    xb[row * 8 + g] = pack8i8(a, inv);
    if (g == 0) sc[row] = m * (1.f / 127.f);
}

__device__ __forceinline__ int bin_of(int c) { return (c < 63) ? c : 63; }

// exclusive scan of ghist[64] into shared sboff[64] (wave 0); caller syncs.
__device__ __forceinline__ void scan_boff(const int* __restrict__ ghist, int* sboff) {
    int t = threadIdx.x;
    if (t < 64) {
        int v = ghist[t];
        int s = v;
        for (int o = 1; o < 64; o <<= 1) {
            int u = __shfl_up(s, o);
            if (t >= o) s += u;
        }
        sboff[t] = s - v;
    }
}

// ================= role device functions (bid = role-local block id) =================

// count+rank over edge range [e0,e1): K=8 batched, 1 atomic/edge.
__device__ __forceinline__ void rol_cnt(int bid, const int* __restrict__ dst,
                                        int* __restrict__ cnt, int* __restrict__ rank,
                                        int e0, int e1) {
    int base = e0 + bid * (B * CR_K) + threadIdx.x;
    int d[CR_K];
#pragma unroll
    for (int k = 0; k < CR_K; ++k) {
        int e = base + k * B;
        d[k] = (e < e1) ? dst[e] : 0;
    }
#pragma unroll
    for (int k = 0; k < CR_K; ++k) {
        int e = base + k * B;
        if (e < e1) rank[e] = atomicAdd(&cnt[d[k]], 1);
    }
}

// fp32 -> int8-rowscale conversion (thread = 8 dims), natural order
__device__ __forceinline__ void rol_cvt(int bid, const float4* __restrict__ x,
                                        uint2* __restrict__ xb, float* __restrict__ sc,
                                        int n8) {
    int i = bid * B + threadIdx.x;
    if (i >= n8) return;                       // n8 exact multiple of B in all uses
    float4 a = x[2 * i], b = x[2 * i + 1];
    float t[8] = {a.x, a.y, a.z, a.w, b.x, b.y, b.z, b.w};
    store_row_i8(xb, sc, (size_t)(i >> 3), i & 7, t);
}

// node pass: row-offset scan (order-free alloc) + 64-bin degree histogram + binrank
__device__ void rol_node(int bid, const int* __restrict__ cnt, int2* __restrict__ rr,
                         int* __restrict__ binrank, int* __restrict__ ghist,
                         int* __restrict__ gcur, int N) {
    __shared__ int sh[B];
    __shared__ int h[64], hb[64];
    __shared__ int sbase;
    int t = threadIdx.x;
    int i = bid * B + t;
    int c = (i < N) ? cnt[i] : 0;
    int b = bin_of(c);
    sh[t] = c;
    if (t < 64) h[t] = 0;
    __syncthreads();
    int rk = 0;
    if (i < N) rk = atomicAdd(&h[b], 1);
    for (int off = 1; off < B; off <<= 1) {   // inclusive scan
        int u = (t >= off) ? sh[t - off] : 0;
        __syncthreads();
        sh[t] += u;
        __syncthreads();
    }
    if (t == B - 1) sbase = atomicAdd(gcur, sh[B - 1]);
    if (t < 64) hb[t] = h[t] ? atomicAdd(&ghist[t], h[t]) : 0;
    __syncthreads();
    if (i < N) {
        int o = sbase + sh[t] - c;
        rr[i] = make_int2(o, o + c);
        binrank[i] = hb[b] + rk;
    }
}

// edge fill: coalesced reads, ONE scattered 8B store per edge (raw w payload)
__device__ __forceinline__ void rol_fillE(int bid, const int* __restrict__ src,
                                          const int* __restrict__ dst,
                                          const float* __restrict__ w,
                                          const int* __restrict__ rank,
                                          const int2* __restrict__ rr,
                                          int2* __restrict__ ev, int E) {
    int base = bid * (B * FE_K) + threadIdx.x;
    int d[FE_K], r[FE_K], s[FE_K];
    float ww[FE_K];
#pragma unroll
    for (int k = 0; k < FE_K; ++k) {
        int e = base + k * B;
        if (e < E) { d[k] = dst[e]; r[k] = rank[e]; s[k] = src[e]; ww[k] = w[e]; }
        else       { d[k] = 0; r[k] = 0; s[k] = 0; ww[k] = 0.f; }
    }
    int pos[FE_K];
#pragma unroll
    for (int k = 0; k < FE_K; ++k) pos[k] = rr[d[k]].x + r[k];
#pragma unroll
    for (int k = 0; k < FE_K; ++k) {
        int e = base + k * B;
        if (e < E) ev[pos[k]] = make_int2(s[k], __float_as_int(ww[k]));
    }
}

// weighted degree from CSR; dis = rsqrt(deg) or 0
__device__ __forceinline__ void rol_deg(int bid, const int2* __restrict__ rr,
                                        const int2* __restrict__ ev,
                                        float* __restrict__ dis, int N) {
    int i = bid * B + threadIdx.x;
    if (i >= N) return;
    int2 se = rr[i];
    float dg = 0.f;
    for (int j = se.x; j < se.y; ++j) dg += __int_as_float(ev[j].y);
    dis[i] = (dg > 0.f) ? rsqrtf(dg) : 0.f;
}

// g1: normalize ev in place + degree-sorted permutation scatter
__device__ void rol_valsc(int bid, const int2* __restrict__ rr, const float* __restrict__ dis,
                          const int* __restrict__ binrank, const int* __restrict__ ghist,
                          int2* __restrict__ ev, int* __restrict__ perm,
                          int2* __restrict__ rrp, int N) {
    __shared__ int sboff[64];
    scan_boff(ghist, sboff);
    __syncthreads();
    int i = bid * B + threadIdx.x;
    if (i >= N) return;
    int2 se = rr[i];
    float di = dis[i];
    for (int j = se.x; j < se.y; ++j) {
        int2 p = ev[j];
        ev[j].y = __float_as_int(di * __int_as_float(p.y) * dis[p.x]);
    }
    int pos = sboff[bin_of(se.y - se.x)] + binrank[i];
    perm[pos] = i;
    rrp[pos]  = se;
}

// g2: sort finalize: sortpos[i] (linear), perm[pos]=i, srr[pos]=rr[i]
__device__ void rol_sortfin(int bid, const int2* __restrict__ rr, const int* __restrict__ brk,
                            const int* __restrict__ ghist, int* __restrict__ sortpos,
                            int* __restrict__ perm, int2* __restrict__ srr, int N) {
    __shared__ int sboff[64];
    scan_boff(ghist, sboff);
    __syncthreads();
    int i = bid * B + threadIdx.x;
    if (i >= N) return;
    int2 se = rr[i];
    int pos = sboff[bin_of(se.y - se.x)] + brk[i];
    sortpos[i] = pos;
    perm[pos] = i;
    srr[pos]  = se;
}

// g2: normalize ev + remap ev.x into sorted space
__device__ __forceinline__ void rol_evnorm(int bid, const int2* __restrict__ rr,
                                           const float* __restrict__ dis,
                                           const int* __restrict__ sortpos,
                                           int2* __restrict__ ev, int N) {
    int i = bid * B + threadIdx.x;
    if (i >= N) return;
    int2 se = rr[i];
    float di = dis[i];
    for (int j = se.x; j < se.y; ++j) {
        int2 p = ev[j];
        ev[j] = make_int2(sortpos[p.x],
                          __float_as_int(di * __int_as_float(p.y) * dis[p.x]));
    }
}

// g2: fp32 user rows -> int8 directly into SORTED x0 table (inline pos calc)
__device__ void rol_cvts(int bid, const float4* __restrict__ xu,
                         const int2* __restrict__ rr2, const int* __restrict__ brk2,
                         const int* __restrict__ ghist2, uint2* __restrict__ xb0s,
                         float* __restrict__ sc0, int Nrows) {
    __shared__ int sboff[64];
    scan_boff(ghist2, sboff);
    __syncthreads();
    int idx = bid * B + threadIdx.x;
    int row = idx >> 3;
    if (row >= Nrows) return;                  // exact multiple — all lanes active
    int g = idx & 7;
    int2 s2 = rr2[row];
    int pos = sboff[bin_of(s2.y - s2.x)] + brk2[row];
    float4 a = xu[(size_t)row * 16 + 2 * g], b = xu[(size_t)row * 16 + 2 * g + 1];
    float t[8] = {a.x, a.y, a.z, a.w, b.x, b.y, b.z, b.w};
    store_row_i8(xb0s, sc0, (size_t)pos, g, t);
}

// pull SpMM g1 (orig-space scheme, perm indirection), int8 tables
__device__ void rol_spmm(int bid, const int2* __restrict__ rrp, const int* __restrict__ perm,
                         const int2* __restrict__ ev, const uint2* __restrict__ xb,
                         const float* __restrict__ sci, uint2* __restrict__ xn,
                         float* __restrict__ sco, int N) {
    int idx = bid * B + threadIdx.x;
    int vrow = idx >> 3;
    if (vrow >= N) return;
    int g = idx & 7;
    int2 se = rrp[vrow];
    int row = perm[vrow];
    float acc[8] = {0.f, 0.f, 0.f, 0.f, 0.f, 0.f, 0.f, 0.f};
    int j = se.x, e = se.y;
    for (; j + 3 < e; j += 4) {
        int2 p0 = ev[j], p1 = ev[j + 1], p2 = ev[j + 2], p3 = ev[j + 3];
        uint2 a0 = xb[(size_t)p0.x * 8 + g];
        uint2 a1 = xb[(size_t)p1.x * 8 + g];
        uint2 a2 = xb[(size_t)p2.x * 8 + g];
        uint2 a3 = xb[(size_t)p3.x * 8 + g];
        float s0 = sci[p0.x], s1 = sci[p1.x], s2 = sci[p2.x], s3 = sci[p3.x];
        i8_fma(acc, a0, __int_as_float(p0.y) * s0);
        i8_fma(acc, a1, __int_as_float(p1.y) * s1);
        i8_fma(acc, a2, __int_as_float(p2.y) * s2);
        i8_fma(acc, a3, __int_as_float(p3.y) * s3);
    }
    for (; j < e; ++j) {
        int2 p0 = ev[j];
        uint2 a0 = xb[(size_t)p0.x * 8 + g];
        i8_fma(acc, a0, __int_as_float(p0.y) * sci[p0.x]);
    }
    store_row_i8(xn, sco, (size_t)row, g, acc);
}

// pull SpMM g2 (sorted space): linear srr read, linear xn write, int8 tables
__device__ void rol_spmm_s(int bid, const int2* __restrict__ srr, const int2* __restrict__ ev,
                           const uint2* __restrict__ xb, const float* __restrict__ sci,
                           uint2* __restrict__ xn, float* __restrict__ sco, int N) {
    int idx = bid * B + threadIdx.x;
    int vrow = idx >> 3;
    if (vrow >= N) return;
    int g = idx & 7;
    int2 se = srr[vrow];
    float acc[8] = {0.f, 0.f, 0.f, 0.f, 0.f, 0.f, 0.f, 0.f};
    int j = se.x, e = se.y;
    for (; j + 3 < e; j += 4) {
        int2 p0 = ev[j], p1 = ev[j + 1], p2 = ev[j + 2], p3 = ev[j + 3];
        uint2 a0 = xb[(size_t)p0.x * 8 + g];
        uint2 a1 = xb[(size_t)p1.x * 8 + g];
        uint2 a2 = xb[(size_t)p2.x * 8 + g];
        uint2 a3 = xb[(size_t)p3.x * 8 + g];
        float s0 = sci[p0.x], s1 = sci[p1.x], s2 = sci[p2.x], s3 = sci[p3.x];
        i8_fma(acc, a0, __int_as_float(p0.y) * s0);
        i8_fma(acc, a1, __int_as_float(p1.y) * s1);
        i8_fma(acc, a2, __int_as_float(p2.y) * s2);
        i8_fma(acc, a3, __int_as_float(p3.y) * s3);
    }
    for (; j < e; ++j) {
        int2 p0 = ev[j];
        uint2 a0 = xb[(size_t)p0.x * 8 + g];
        i8_fma(acc, a0, __int_as_float(p0.y) * sci[p0.x]);
    }
    store_row_i8(xn, sco, (size_t)vrow, g, acc);
}

// g1 final: res = alpha*(x0+x1+x2+A*x2); writes int8 item rows DIRECTLY into
// g2's sorted x0 table at inline-computed sort positions.
__device__ void rol_final1(int bid, const int2* __restrict__ rrp, const int* __restrict__ perm,
                           const int2* __restrict__ ev,
                           const uint2* __restrict__ x2b, const float* __restrict__ sc2,
                           const uint2* __restrict__ x1b, const float* __restrict__ sc1,
                           const uint2* __restrict__ x0b, const float* __restrict__ sc0,
                           const int2* __restrict__ rr2, const int* __restrict__ brk2,
                           const int* __restrict__ ghist2, uint2* __restrict__ xb0s,
                           float* __restrict__ sc0s, float alpha, int N) {
    __shared__ int sboff[64];
    scan_boff(ghist2, sboff);
    __syncthreads();
    int idx = bid * B + threadIdx.x;
    int vrow = idx >> 3;
    if (vrow >= N) return;                     // exact multiple — all lanes active
    int g = idx & 7;
    int2 se = rrp[vrow];
    int row = perm[vrow];
    float acc[8] = {0.f, 0.f, 0.f, 0.f, 0.f, 0.f, 0.f, 0.f};
    int j = se.x, e = se.y;
    for (; j + 3 < e; j += 4) {
        int2 p0 = ev[j], p1 = ev[j + 1], p2 = ev[j + 2], p3 = ev[j + 3];
        uint2 a0 = x2b[(size_t)p0.x * 8 + g];
        uint2 a1 = x2b[(size_t)p1.x * 8 + g];
        uint2 a2 = x2b[(size_t)p2.x * 8 + g];
        uint2 a3 = x2b[(size_t)p3.x * 8 + g];
        float s0 = sc2[p0.x], s1 = sc2[p1.x], s2 = sc2[p2.x], s3 = sc2[p3.x];
        i8_fma(acc, a0, __int_as_float(p0.y) * s0);
        i8_fma(acc, a1, __int_as_float(p1.y) * s1);
        i8_fma(acc, a2, __int_as_float(p2.y) * s2);
        i8_fma(acc, a3, __int_as_float(p3.y) * s3);
    }
    for (; j < e; ++j) {
        int2 p0 = ev[j];
        uint2 a0 = x2b[(size_t)p0.x * 8 + g];
        i8_fma(acc, a0, __int_as_float(p0.y) * sc2[p0.x]);
    }
    i8_fma(acc, x1b[(size_t)row * 8 + g], sc1[row]);
    i8_fma(acc, x2b[(size_t)row * 8 + g], sc2[row]);
    i8_fma(acc, x0b[(size_t)row * 8 + g], sc0[row]);
    float r[8];
#pragma unroll
    for (int k = 0; k < 8; ++k) r[k] = alpha * acc[k];
    int oi = N_USERS + row;                    // orig id in g2 space
    int2 s2r = rr2[oi];
    int pos = sboff[bin_of(s2r.y - s2r.x)] + brk2[oi];
    store_row_i8(xb0s, sc0s, (size_t)pos, g, r);
}

// g2 final (sorted space): linear adds; out[perm[vrow]] fp32 scatter (no quant)
__device__ void rol_final_s(int bid, const int2* __restrict__ srr, const int* __restrict__ perm,
                            const int2* __restrict__ ev,
                            const uint2* __restrict__ x2s, const float* __restrict__ sc2,
                            const uint2* __restrict__ x1s, const float* __restrict__ sc1,
                            const uint2* __restrict__ x0s, const float* __restrict__ sc0,
                            float4* __restrict__ out, float alpha, int N) {
    int idx = bid * B + threadIdx.x;
    int vrow = idx >> 3;
    if (vrow >= N) return;
    int g = idx & 7;
    int2 se = srr[vrow];
    float acc[8] = {0.f, 0.f, 0.f, 0.f, 0.f, 0.f, 0.f, 0.f};
    int j = se.x, e = se.y;
    for (; j + 3 < e; j += 4) {
        int2 p0 = ev[j], p1 = ev[j + 1], p2 = ev[j + 2], p3 = ev[j + 3];
        uint2 a0 = x2s[(size_t)p0.x * 8 + g];
        uint2 a1 = x2s[(size_t)p1.x * 8 + g];
        uint2 a2 = x2s[(size_t)p2.x * 8 + g];
        uint2 a3 = x2s[(size_t)p3.x * 8 + g];
        float s0 = sc2[p0.x], s1 = sc2[p1.x], s2 = sc2[p2.x], s3 = sc2[p3.x];
        i8_fma(acc, a0, __int_as_float(p0.y) * s0);
        i8_fma(acc, a1, __int_as_float(p1.y) * s1);
        i8_fma(acc, a2, __int_as_float(p2.y) * s2);
        i8_fma(acc, a3, __int_as_float(p3.y) * s3);
    }
    for (; j < e; ++j) {
        int2 p0 = ev[j];
        uint2 a0 = x2s[(size_t)p0.x * 8 + g];
        i8_fma(acc, a0, __int_as_float(p0.y) * sc2[p0.x]);
    }
    i8_fma(acc, x1s[(size_t)vrow * 8 + g], sc1[vrow]);
    i8_fma(acc, x2s[(size_t)vrow * 8 + g], sc2[vrow]);
    i8_fma(acc, x0s[(size_t)vrow * 8 + g], sc0[vrow]);
    float r[8];
#pragma unroll
    for (int k = 0; k < 8; ++k) r[k] = alpha * acc[k];
    int orig = perm[vrow];
    out[(size_t)orig * 16 + 2 * g]     = make_float4(r[0], r[1], r[2], r[3]);
    out[(size_t)orig * 16 + 2 * g + 1] = make_float4(r[4], r[5], r[6], r[7]);
}

// ================= fused dispatch kernels (blockIdx range -> role, R12 scheme) =================

__global__ void f_cnt_cvt(int nbA, const int* dstA, int* cntA, int* rankA, int eA,
                          const float4* xB, uint2* xbB, float* scB, int n8B) {
    int b = (int)blockIdx.x;
    if (b < nbA) rol_cnt(b, dstA, cntA, rankA, 0, eA);
    else         rol_cvt(b - nbA, xB, xbB, scB, n8B);
}

__global__ void f_node_cnt(int nbA, const int* cntN, int2* rr, int* brk, int* ghist,
                           int* gcur, int N,
                           const int* dstS, int* cntS, int* rankS, int e0, int e1) {
    int b = (int)blockIdx.x;
    if (b < nbA) rol_node(b, cntN, rr, brk, ghist, gcur, N);
    else         rol_cnt(b - nbA, dstS, cntS, rankS, e0, e1);
}

__global__ void f_fillE_cnt(int nbA, const int* src, const int* dst, const float* w,
                            const int* rank, const int2* rr, int2* ev, int E,
                            const int* dstS, int* cntS, int* rankS, int e0, int e1) {
    int b = (int)blockIdx.x;
    if (b < nbA) rol_fillE(b, src, dst, w, rank, rr, ev, E);
    else         rol_cnt(b - nbA, dstS, cntS, rankS, e0, e1);
}

__global__ void f_deg_cnt(int nbA, const int2* rr, const int2* ev, float* dis, int N,
                          const int* dstS, int* cntS, int* rankS, int e0, int e1) {
    int b = (int)blockIdx.x;
    if (b < nbA) rol_deg(b, rr, ev, dis, N);
    else         rol_cnt(b - nbA, dstS, cntS, rankS, e0, e1);
}

__global__ void f_valsc_cnt(int nbA, const int2* rr, const float* dis, const int* brk,
                            const int* ghist, int2* ev, int* perm, int2* rrp, int N,
                            const int* dstS, int* cntS, int* rankS, int e0, int e1) {
    int b = (int)blockIdx.x;
    if (b < nbA) rol_valsc(b, rr, dis, brk, ghist, ev, perm, rrp, N);
    else         rol_cnt(b - nbA, dstS, cntS, rankS, e0, e1);
}

__global__ void f_spmm_cnt(int nbA, const int2* rrp, const int* perm, const int2* ev,
                           const uint2* xb, const float* sci, uint2* xn, float* sco, int NA,
                           const int* dstS, int* cntS, int* rankS, int e0, int e1) {
    int b = (int)blockIdx.x;
    if (b < nbA) rol_spmm(b, rrp, perm, ev, xb, sci, xn, sco, NA);
    else         rol_cnt(b - nbA, dstS, cntS, rankS, e0, e1);
}

__global__ void f_spmm_node(int nbA, const int2* rrp, const int* perm, const int2* ev,
                            const uint2* xb, const float* sci, uint2* xn, float* sco, int NA,
                            const int* cntN, int2* rrB, int* brkB, int* ghistB,
                            int* gcurB, int NB) {
    int b = (int)blockIdx.x;
    if (b < nbA) rol_spmm(b, rrp, perm, ev, xb, sci, xn, sco, NA);
    else         rol_node(b - nbA, cntN, rrB, brkB, ghistB, gcurB, NB);
}

// F8: [final1 | cvt2u_sorted | deg2 | sortfin2]
__global__ void f_final_mix(int nbA, const int2* rrp1, const int* perm1, const int2* ev1,
                            const uint2* x2b, const float* sc12,
                            const uint2* x1b, const float* sc11,
                            const uint2* x0b, const float* sc10,
                            float alpha, int N1,
                            int nbB, const float4* xu,
                            int nbC, const int2* rr2, const int2* ev2, float* dis2, int N2,
                            const int* brk2, const int* ghist2,
                            uint2* xb0s, float* sc20,
                            int* sortpos2, int* perm2, int2* srr2) {
    int b = (int)blockIdx.x;
    if (b < nbA) { rol_final1(b, rrp1, perm1, ev1, x2b, sc12, x1b, sc11, x0b, sc10,
                              rr2, brk2, ghist2, xb0s, sc20, alpha, N1); return; }
    b -= nbA;
    if (b < nbB) { rol_cvts(b, xu, rr2, brk2, ghist2, xb0s, sc20, N_USERS); return; }
    b -= nbB;
    if (b < nbC) { rol_deg(b, rr2, ev2, dis2, N2); return; }
    rol_sortfin(b - nbC, rr2, brk2, ghist2, sortpos2, perm2, srr2, N2);
}

// plain single-role kernels
__global__ void k_fill(const int* src, const int* dst, const float* w, const int* rank,
                       const int2* rr, int2* ev, int E) {
    rol_fillE((int)blockIdx.x, src, dst, w, rank, rr, ev, E);
}
__global__ void k_evnorm(const int2* rr, const float* dis, const int* sortpos,
                         int2* ev, int N) {
    rol_evnorm((int)blockIdx.x, rr, dis, sortpos, ev, N);
}
__global__ void k_spmm_s(const int2* srr, const int2* ev, const uint2* xb, const float* sci,
                         uint2* xn, float* sco, int N) {
    rol_spmm_s((int)blockIdx.x, srr, ev, xb, sci, xn, sco, N);
}
__global__ void k_final_s(const int2* srr, const int* perm, const int2* ev,
                          const uint2* x2s, const float* sc2,
                          const uint2* x1s, const float* sc1,
                          const uint2* x0s, const float* sc0,
                          float4* out, float alpha, int N) {
    rol_final_s((int)blockIdx.x, srr, perm, ev, x2s, sc2, x1s, sc1, x0s, sc0,
                out, alpha, N);
}

// ================= host-side orchestration =================

static inline int nbx(long long work, int per) { return (int)((work + per - 1) / per); }

extern "C" void kernel_launch(void* const* d_in, const int* in_sizes, int n_in,
                              void* d_out, int out_size, void* d_ws, size_t ws_size,
                              hipStream_t stream) {
    const float* emb_ii  = (const float*)d_in[0];
    const float* emb_uiu = (const float*)d_in[1];
    const float* w_ii    = (const float*)d_in[2];
    const float* w_uiu   = (const float*)d_in[3];
    const int*   src_ii  = (const int*)d_in[4];
    const int*   dst_ii  = src_ii + E_II;
    const int*   src_uiu = (const int*)d_in[5];
    const int*   dst_uiu = src_uiu + E_UIU;
    float*       out     = (float*)d_out;

    // ---- workspace (~93.2 MB, int8 tables + scales; NO aliasing) ----
    uint2* xb0_u = (uint2*)d_ws;                       // g2 sorted x0 (12.8MB)
    uint2* x1_u  = xb0_u + (size_t)N_UIU * 8;          // g2 z1
    uint2* x2_u  = x1_u + (size_t)N_UIU * 8;           // g2 z2
    uint2* g1_x0 = x2_u + (size_t)N_UIU * 8;           // g1 tables (6.4MB each)
    uint2* g1_x1 = g1_x0 + (size_t)N_II * 8;
    uint2* g1_x2 = g1_x1 + (size_t)N_II * 8;

    float* sc20  = (float*)(g1_x2 + (size_t)N_II * 8); // g2 scales (sorted space)
    float* sc21  = sc20 + N_UIU;
    float* sc22  = sc21 + N_UIU;
    float* sc10  = sc22 + N_UIU;                       // g1 scales (orig space)
    float* sc11  = sc10 + N_II;
    float* sc12  = sc11 + N_II;

    int2*  ev1   = (int2*)(sc12 + N_II);
    int*   rank1 = (int*)(ev1 + E_II);
    int2*  rr1   = (int2*)(rank1 + E_II);
    int*   cnt1  = (int*)(rr1 + N_II);                 // + gt1[129] tail
    int*   gt1   = cnt1 + N_II;
    float* dis1  = (float*)(cnt1 + N_II + 129);
    int*   brk1  = (int*)(dis1 + N_II);
    int*   perm1 = brk1 + N_II;
    int2*  rrp1  = (int2*)(perm1 + N_II);

    int2*  ev2   = (int2*)(rrp1 + N_II);
    int*   rank2 = (int*)(ev2 + E_UIU);
    int2*  rr2   = (int2*)(rank2 + E_UIU);
    int*   cnt2  = (int*)(rr2 + N_UIU);                // + gt2[129] tail
    int*   gt2   = cnt2 + N_UIU;
    float* dis2  = (float*)(cnt2 + N_UIU + 129);
    int*   brk2  = (int*)(dis2 + N_UIU);
    int*   perm2 = brk2 + N_UIU;
    int2*  srr2  = (int2*)(perm2 + N_UIU);
    int*   sortpos2 = (int*)(srr2 + N_UIU);

    const float alpha = 0.25f;    // 1/(L+1), L=3 both graphs

    hipMemsetAsync(cnt1, 0, ((size_t)N_II + 129) * sizeof(int), stream);
    hipMemsetAsync(cnt2, 0, ((size_t)N_UIU + 129) * sizeof(int), stream);

    // cnt2 slices: 5 chunks across F1-F5 (R12 scheme)
    const int s[6] = {0, 240000, 480000, 720000, 960000, E_UIU};

    const int nbCnt1 = nbx(E_II, B * CR_K);
    const int nbCvt1 = nbx((long long)N_II * 8, B);
    const int nbN1   = nbx(N_II, B);
    const int nbF1   = nbx(E_II, B * FE_K);
    const int nbS1   = nbx((long long)N_II * 8, B);
    const int nbN2   = nbx(N_UIU, B);
    const int nbF2   = nbx(E_UIU, B * FE_K);
    const int nbS2   = nbx((long long)N_UIU * 8, B);
    const int nbCvt2 = nbx((long long)N_USERS * 8, B);

    // F0: g1 count | g1 x0 int8 conversion
    f_cnt_cvt<<<nbCnt1 + nbCvt1, B, 0, stream>>>(
        nbCnt1, dst_ii, cnt1, rank1, E_II,
        (const float4*)emb_ii, g1_x0, sc10, N_II * 8);

    // F1: g1 node | cnt2 slice 0
    f_node_cnt<<<nbN1 + nbx(s[1] - s[0], B * CR_K), B, 0, stream>>>(
        nbN1, cnt1, rr1, brk1, gt1 + 1, gt1, N_II,
        dst_uiu, cnt2, rank2, s[0], s[1]);

    // F2: g1 fillE | cnt2 slice 1
    f_fillE_cnt<<<nbF1 + nbx(s[2] - s[1], B * CR_K), B, 0, stream>>>(
        nbF1, src_ii, dst_ii, w_ii, rank1, rr1, ev1, E_II,
        dst_uiu, cnt2, rank2, s[1], s[2]);

    // F3: g1 deg | cnt2 slice 2
    f_deg_cnt<<<nbN1 + nbx(s[3] - s[2], B * CR_K), B, 0, stream>>>(
        nbN1, rr1, ev1, dis1, N_II,
        dst_uiu, cnt2, rank2, s[2], s[3]);

    // F4: g1 val+scatter | cnt2 slice 3
    f_valsc_cnt<<<nbN1 + nbx(s[4] - s[3], B * CR_K), B, 0, stream>>>(
        nbN1, rr1, dis1, brk1, gt1 + 1, ev1, perm1, rrp1, N_II,
        dst_uiu, cnt2, rank2, s[3], s[4]);

    // F5: g1 spmm layer1 | cnt2 slice 4 (cnt2 complete)
    f_spmm_cnt<<<nbS1 + nbx(s[5] - s[4], B * CR_K), B, 0, stream>>>(
        nbS1, rrp1, perm1, ev1, g1_x0, sc10, g1_x1, sc11, N_II,
        dst_uiu, cnt2, rank2, s[4], s[5]);

    // F6: g1 spmm layer2 | g2 node
    f_spmm_node<<<nbS1 + nbN2, B, 0, stream>>>(
        nbS1, rrp1, perm1, ev1, g1_x1, sc11, g1_x2, sc12, N_II,
        cnt2, rr2, brk2, gt2 + 1, gt2, N_UIU);

    // F7: g2 fillE ALONE (scatter-store role; no cache-sensitive co-tenant)
    k_fill<<<nbF2, B, 0, stream>>>(src_uiu, dst_uiu, w_uiu, rank2, rr2, ev2, E_UIU);

    // F8: g1 final (-> sorted g2 x0) | cvt2u sorted | g2 deg | g2 sortfin
    f_final_mix<<<nbS1 + nbCvt2 + nbN2 + nbN2, B, 0, stream>>>(
        nbS1, rrp1, perm1, ev1, g1_x2, sc12, g1_x1, sc11, g1_x0, sc10, alpha, N_II,
        nbCvt2, (const float4*)emb_uiu,
        nbN2, rr2, ev2, dis2, N_UIU,
        brk2, gt2 + 1, xb0_u, sc20, sortpos2, perm2, srr2);

    // F9: g2 evnorm (normalize + remap ev.x -> sorted)
    k_evnorm<<<nbN2, B, 0, stream>>>(rr2, dis2, sortpos2, ev2, N_UIU);

    // F10-F12: g2 spmm chain in sorted space (int8 tables)
    k_spmm_s<<<nbS2, B, 0, stream>>>(srr2, ev2, xb0_u, sc20, x1_u, sc21, N_UIU);
    k_spmm_s<<<nbS2, B, 0, stream>>>(srr2, ev2, x1_u, sc21, x2_u, sc22, N_UIU);
    k_final_s<<<nbS2, B, 0, stream>>>(srr2, perm2, ev2, x2_u, sc22, x1_u, sc21,
                                      xb0_u, sc20, (float4*)out, alpha, N_UIU);
}